// Round 5
// baseline (100.461 us; speedup 1.0000x reference)
//
#include <hip/hip_runtime.h>
#include <math.h>

// Tropical (min-plus) matmul: out[b, j] = min_i (X[b, i] + W[j, i])
// X: [1024][512] fp32, W: [512][512] fp32, out: [1024][512] fp32.
//
// Round 5: W lane-resident in VGPRs (loaded once, coalesced via WT4 pack);
// X delivered by LDS uniform-address broadcast ds_read_b128 (in-order,
// compiler-pipelined via counted lgkmcnt — unlike SMEM's out-of-order drain).
//  - Block: 8 waves. Wave w owns k-chunk [64w, 64w+64), lane = j.
//  - X tile [16][512] staged coalesced into LDS once per block (32 KB).
//  - Per b-row: 16x ds_read_b128 (broadcast) + 96 VALU (v_add + v_min3).
//  - k-chunk partials combined through LDS, one barrier.
//  - Grid 8x64 = 512 blocks = 2/CU = 16 waves/CU (LDS 64 KB/block, VGPR<=128).

#define B_DIM   1024
#define IN_DIM  512
#define OUT_DIM 512

// ---------------- prepass: WT4[k4][j] = { W[j][4k4..4k4+3] } ----------------
__global__ __launch_bounds__(256)
void MinPlus_wt4_pack(const float* __restrict__ W, float4* __restrict__ WT4) {
    __shared__ float Ls[64][68];
    const int tid = threadIdx.x;
    const int j0 = blockIdx.x * 64;
    const int k0 = blockIdx.y * 64;

#pragma unroll
    for (int r = 0; r < 4; ++r) {
        const int jj = (tid >> 4) + r * 16;
        const int kq = tid & 15;
        const float4 v = *reinterpret_cast<const float4*>(&W[(j0 + jj) * IN_DIM + k0 + 4 * kq]);
        *reinterpret_cast<float4*>(&Ls[jj][4 * kq]) = v;
    }
    __syncthreads();

    const int jj  = tid & 63;
    const int k4b = tid >> 6;
#pragma unroll
    for (int r = 0; r < 4; ++r) {
        const int k4l = r * 4 + k4b;
        const float4 v = *reinterpret_cast<const float4*>(&Ls[jj][4 * k4l]);
        WT4[(size_t)(blockIdx.y * 16 + k4l) * OUT_DIM + j0 + jj] = v;
    }
}

// ---------------- main ----------------
__global__ __launch_bounds__(512, 4)
void MinPlus_70832600646269_kernel(const float* __restrict__ X,
                                   const float4* __restrict__ WT4,
                                   float* __restrict__ out)
{
    __shared__ float Xs[16][IN_DIM];    // 32 KB: X rows b0..b0+15
    __shared__ float part[8][16][64];   // 32 KB: [k-chunk][b][j-lane]

    const int tid  = threadIdx.x;
    const int lane = tid & 63;
    const int wid  = tid >> 6;          // 0..7 = k-chunk id
    const int j0   = blockIdx.x * 64;
    const int b0   = blockIdx.y * 16;

    // ---- W chunk -> 64 VGPRs (once). wr[q] = W[j0+lane][wid*64 + 4q .. +3] ----
    float4 wr[16];
#pragma unroll
    for (int q = 0; q < 16; ++q)
        wr[q] = WT4[(size_t)(wid * 16 + q) * OUT_DIM + j0 + lane];

    // ---- stage X tile: 2048 float4, 512 threads -> 4 each, fully coalesced ----
    {
        const float4* __restrict__ src = reinterpret_cast<const float4*>(X + (size_t)b0 * IN_DIM);
        float4* dst = reinterpret_cast<float4*>(&Xs[0][0]);
#pragma unroll
        for (int i = 0; i < 4; ++i)
            dst[tid + i * 512] = src[tid + i * 512];
    }
    __syncthreads();

    // ---- main loop: per b-row, 16x uniform-address ds_read_b128 + compute ----
    for (int b = 0; b < 16; ++b) {
        const float4* __restrict__ xrow = reinterpret_cast<const float4*>(&Xs[b][wid * 64]);

        float a0 = INFINITY, a1 = INFINITY, a2 = INFINITY, a3 = INFINITY;

#pragma unroll
        for (int q = 0; q < 16; q += 4) {
            const float4 x0 = xrow[q + 0];
            const float4 x1 = xrow[q + 1];
            const float4 x2 = xrow[q + 2];
            const float4 x3 = xrow[q + 3];
            const float4 w0 = wr[q + 0];
            const float4 w1 = wr[q + 1];
            const float4 w2 = wr[q + 2];
            const float4 w3 = wr[q + 3];

            a0 = fminf(fminf(a0, w0.x + x0.x), w0.y + x0.y);   // v_min3
            a0 = fminf(fminf(a0, w0.z + x0.z), w0.w + x0.w);
            a1 = fminf(fminf(a1, w1.x + x1.x), w1.y + x1.y);
            a1 = fminf(fminf(a1, w1.z + x1.z), w1.w + x1.w);
            a2 = fminf(fminf(a2, w2.x + x2.x), w2.y + x2.y);
            a2 = fminf(fminf(a2, w2.z + x2.z), w2.w + x2.w);
            a3 = fminf(fminf(a3, w3.x + x3.x), w3.y + x3.y);
            a3 = fminf(fminf(a3, w3.z + x3.z), w3.w + x3.w);
        }

        part[wid][b][lane] = fminf(fminf(a0, a1), fminf(a2, a3));
    }

    __syncthreads();

    // ---- combine 8 k-chunks; wave wid handles b = 2*wid, 2*wid+1 ----
#pragma unroll
    for (int r = 0; r < 2; ++r) {
        const int b = wid * 2 + r;
        float m = part[0][b][lane];
#pragma unroll
        for (int p = 1; p < 8; ++p) m = fminf(m, part[p][b][lane]);
        out[(size_t)(b0 + b) * OUT_DIM + j0 + lane] = m;
    }
}

extern "C" void kernel_launch(void* const* d_in, const int* in_sizes, int n_in,
                              void* d_out, int out_size, void* d_ws, size_t ws_size,
                              hipStream_t stream) {
    const float* X = (const float*)d_in[0];
    const float* W = (const float*)d_in[1];
    float* out = (float*)d_out;
    float4* WT4 = (float4*)d_ws;   // 128 * 512 float4 = 1 MiB

    MinPlus_wt4_pack<<<dim3(OUT_DIM / 64, IN_DIM / 64), 256, 0, stream>>>(W, WT4);

    MinPlus_70832600646269_kernel<<<dim3(OUT_DIM / 64, B_DIM / 16), 512, 0, stream>>>(X, WT4, out);
}

// Round 6
// 27.526 us; speedup vs baseline: 3.6496x; 3.6496x over previous
//
#include <hip/hip_runtime.h>
#include <math.h>

// Tropical (min-plus) matmul: out[b, j] = min_i (X[b, i] + W[j, i])
// X: [1024][512] fp32, W: [512][512] fp32, out: [1024][512] fp32.
//
// Round 6: round-5 structure, two fixes.
//  (1) NO second __launch_bounds__ arg — round 5's (512,4) capped VGPRs at 64
//      (observed VGPR_Count=64 + 56 MB scratch writes = wr[] spilled).
//      1024-thread block is launchability-capped at 128 VGPR, which fits.
//  (2) TN=2: each lane owns j and j+64 -> every broadcast X value feeds 2 adds
//      -> LDS:VALU instr ratio 1:12 (was 1:6), LDS pipe off the critical path.
// Structure: 16 waves/block; wave w owns k-chunk [32w, 32w+32) with W resident
// in 64 VGPRs (loaded once, coalesced via WT4 pack); X tile [8][512] staged
// coalesced to LDS once, read as uniform-address (broadcast) ds_read_b128;
// per-k-chunk partials combined through LDS with one barrier.
// Grid 4x128 = 512 blocks; 1 block/CU (80 KB LDS), 16 waves/CU, 2 rounds.

#define B_DIM   1024
#define IN_DIM  512
#define OUT_DIM 512

// ---------------- prepass: WT4[k4][j] = { W[j][4k4..4k4+3] } ----------------
__global__ __launch_bounds__(256)
void MinPlus_wt4_pack(const float* __restrict__ W, float4* __restrict__ WT4) {
    __shared__ float Ls[64][68];
    const int tid = threadIdx.x;
    const int j0 = blockIdx.x * 64;
    const int k0 = blockIdx.y * 64;

#pragma unroll
    for (int r = 0; r < 4; ++r) {
        const int jj = (tid >> 4) + r * 16;
        const int kq = tid & 15;
        const float4 v = *reinterpret_cast<const float4*>(&W[(j0 + jj) * IN_DIM + k0 + 4 * kq]);
        *reinterpret_cast<float4*>(&Ls[jj][4 * kq]) = v;
    }
    __syncthreads();

    const int jj  = tid & 63;
    const int k4b = tid >> 6;
#pragma unroll
    for (int r = 0; r < 4; ++r) {
        const int k4l = r * 4 + k4b;
        const float4 v = *reinterpret_cast<const float4*>(&Ls[jj][4 * k4l]);
        WT4[(size_t)(blockIdx.y * 16 + k4l) * OUT_DIM + j0 + jj] = v;
    }
}

// ---------------- main ----------------
__global__ __launch_bounds__(1024)
void MinPlus_70832600646269_kernel(const float* __restrict__ X,
                                   const float4* __restrict__ WT4,
                                   float* __restrict__ out)
{
    __shared__ float Xs[8][IN_DIM];      // 16 KB: X rows b0..b0+7
    __shared__ float part[16][8][128];   // 64 KB: [k-chunk][b][j-local]

    const int tid  = threadIdx.x;
    const int lane = tid & 63;
    const int wid  = tid >> 6;           // 0..15 = k-chunk id (32 k each)
    const int j0   = blockIdx.x * 128;
    const int b0   = blockIdx.y * 8;

    // ---- W resident: lane owns columns j0+lane and j0+64+lane, k in [32wid, 32wid+32) ----
    float4 w0[8], w1[8];
#pragma unroll
    for (int q = 0; q < 8; ++q) {
        w0[q] = WT4[(size_t)(wid * 8 + q) * OUT_DIM + j0 + lane];
        w1[q] = WT4[(size_t)(wid * 8 + q) * OUT_DIM + j0 + 64 + lane];
    }

    // ---- stage X tile: 1024 float4, 1024 threads -> 1 each, fully coalesced ----
    reinterpret_cast<float4*>(&Xs[0][0])[tid] =
        reinterpret_cast<const float4*>(X + (size_t)b0 * IN_DIM)[tid];
    __syncthreads();

    // ---- main loop: per b-row, 8x uniform-address (broadcast) ds_read_b128 ----
    for (int b = 0; b < 8; ++b) {
        const float4* __restrict__ xrow = reinterpret_cast<const float4*>(&Xs[b][wid * 32]);

        float a0 = INFINITY, a1 = INFINITY;
#pragma unroll
        for (int q = 0; q < 8; ++q) {
            const float4 x = xrow[q];
            const float4 u = w0[q];
            const float4 v = w1[q];
            a0 = fminf(fminf(a0, u.x + x.x), u.y + x.y);   // v_min3
            a0 = fminf(fminf(a0, u.z + x.z), u.w + x.w);
            a1 = fminf(fminf(a1, v.x + x.x), v.y + x.y);
            a1 = fminf(fminf(a1, v.z + x.z), v.w + x.w);
        }
        part[wid][b][lane]      = a0;   // consecutive lanes -> consecutive addrs
        part[wid][b][64 + lane] = a1;
    }

    __syncthreads();

    // ---- combine 16 k-chunks; wave wid handles (b = wid>>1, j-half = wid&1) ----
    {
        const int b  = wid >> 1;
        const int jh = (wid & 1) * 64;
        float m = part[0][b][jh + lane];
#pragma unroll
        for (int p = 1; p < 16; ++p) m = fminf(m, part[p][b][jh + lane]);
        out[(size_t)(b0 + b) * OUT_DIM + j0 + jh + lane] = m;
    }
}

extern "C" void kernel_launch(void* const* d_in, const int* in_sizes, int n_in,
                              void* d_out, int out_size, void* d_ws, size_t ws_size,
                              hipStream_t stream) {
    const float* X = (const float*)d_in[0];
    const float* W = (const float*)d_in[1];
    float* out = (float*)d_out;
    float4* WT4 = (float4*)d_ws;   // 128 * 512 float4 = 1 MiB

    MinPlus_wt4_pack<<<dim3(OUT_DIM / 64, IN_DIM / 64), 256, 0, stream>>>(W, WT4);

    MinPlus_70832600646269_kernel<<<dim3(OUT_DIM / 128, B_DIM / 8), 1024, 0, stream>>>(X, WT4, out);
}

// Round 7
// 26.220 us; speedup vs baseline: 3.8315x; 1.0498x over previous
//
#include <hip/hip_runtime.h>
#include <math.h>

// Tropical (min-plus) matmul: out[b, j] = min_i (X[b, i] + W[j, i])
// X: [1024][512] fp32, W: [512][512] fp32, out: [1024][512] fp32.
//
// Round 7: round-6 skeleton with TN=4 (lane owns j0+lane+{0,64,128,192}).
// Rationale: uniform-address ds_read_b128 still pays full return BW
// (~12 cyc/CU per read); TN=2 made LDS pipe 2x the VALU cost. TN=4 gives
// 24 VALU instr per broadcast read = exactly the 12-cyc balance point.
//  - 16 waves (1024 thr); wave wid owns k-chunk [32wid, 32wid+32) as two
//    16-k sub-chunks (W = 16 float4 = 64 VGPR, reloaded once; acc[4][4]
//    persists). ~100 VGPR — fits the 1024-thread 128-VGPR cap, no spills.
//  - b-tile 4: Xs[4][512] = 8 KB staged coalesced; part[16][4][256] = 64 KB.
//  - Grid 2x256 = 512 blocks = 2 rounds, 1 block/CU, 16 waves/CU.
//  - W VMEM: 512 KB/block (disjoint per wave), L2-resident W (1 MB).

#define B_DIM   1024
#define IN_DIM  512
#define OUT_DIM 512

// ---------------- prepass: WT4[k4][j] = { W[j][4k4..4k4+3] } ----------------
__global__ __launch_bounds__(256)
void MinPlus_wt4_pack(const float* __restrict__ W, float4* __restrict__ WT4) {
    __shared__ float Ls[64][68];
    const int tid = threadIdx.x;
    const int j0 = blockIdx.x * 64;
    const int k0 = blockIdx.y * 64;

#pragma unroll
    for (int r = 0; r < 4; ++r) {
        const int jj = (tid >> 4) + r * 16;
        const int kq = tid & 15;
        const float4 v = *reinterpret_cast<const float4*>(&W[(j0 + jj) * IN_DIM + k0 + 4 * kq]);
        *reinterpret_cast<float4*>(&Ls[jj][4 * kq]) = v;
    }
    __syncthreads();

    const int jj  = tid & 63;
    const int k4b = tid >> 6;
#pragma unroll
    for (int r = 0; r < 4; ++r) {
        const int k4l = r * 4 + k4b;
        const float4 v = *reinterpret_cast<const float4*>(&Ls[jj][4 * k4l]);
        WT4[(size_t)(blockIdx.y * 16 + k4l) * OUT_DIM + j0 + jj] = v;
    }
}

// ---------------- main ----------------
__global__ __launch_bounds__(1024)
void MinPlus_70832600646269_kernel(const float* __restrict__ X,
                                   const float4* __restrict__ WT4,
                                   float* __restrict__ out)
{
    __shared__ float Xs[4][IN_DIM];      // 8 KB: X rows b0..b0+3
    __shared__ float part[16][4][256];   // 64 KB: [k-chunk][b][j-local]

    const int tid  = threadIdx.x;
    const int lane = tid & 63;
    const int wid  = tid >> 6;           // 0..15: k4-range [8wid, 8wid+8)
    const int j0   = blockIdx.x * 256;
    const int b0   = blockIdx.y * 4;

    // ---- stage X tile: 512 float4, waves 0..7 load, fully coalesced ----
    if (tid < 512)
        reinterpret_cast<float4*>(&Xs[0][0])[tid] =
            reinterpret_cast<const float4*>(X + (size_t)b0 * IN_DIM)[tid];
    __syncthreads();

    float acc[4][4];                     // [b][jq]
#pragma unroll
    for (int b = 0; b < 4; ++b)
#pragma unroll
        for (int jq = 0; jq < 4; ++jq) acc[b][jq] = INFINITY;

#pragma unroll
    for (int c = 0; c < 2; ++c) {        // two 16-k sub-chunks
        // ---- W sub-chunk -> 64 VGPRs: w[q][jq] = WT4[8wid+4c+q][j0+64jq+lane] ----
        float4 w[4][4];
#pragma unroll
        for (int q = 0; q < 4; ++q)
#pragma unroll
            for (int jq = 0; jq < 4; ++jq)
                w[q][jq] = WT4[(size_t)(wid * 8 + c * 4 + q) * OUT_DIM + j0 + jq * 64 + lane];

#pragma unroll
        for (int b = 0; b < 4; ++b) {
            const float4* __restrict__ xrow =
                reinterpret_cast<const float4*>(&Xs[b][wid * 32 + c * 16]);
#pragma unroll
            for (int q = 0; q < 4; ++q) {
                const float4 x = xrow[q];    // uniform-address broadcast
#pragma unroll
                for (int jq = 0; jq < 4; ++jq) {
                    const float4 u = w[q][jq];
                    acc[b][jq] = fminf(fminf(acc[b][jq], u.x + x.x), u.y + x.y);  // v_min3
                    acc[b][jq] = fminf(fminf(acc[b][jq], u.z + x.z), u.w + x.w);  // v_min3
                }
            }
        }
    }

    // ---- write per-wave partials (consecutive lanes -> consecutive addrs) ----
#pragma unroll
    for (int b = 0; b < 4; ++b)
#pragma unroll
        for (int jq = 0; jq < 4; ++jq)
            part[wid][b][jq * 64 + lane] = acc[b][jq];

    __syncthreads();

    // ---- combine 16 k-chunks: one output per thread ----
    {
        const int b  = tid >> 8;         // 0..3
        const int jj = tid & 255;        // 0..255
        float m = part[0][b][jj];
#pragma unroll
        for (int p = 1; p < 16; ++p) m = fminf(m, part[p][b][jj]);
        out[(size_t)(b0 + b) * OUT_DIM + j0 + jj] = m;
    }
}

extern "C" void kernel_launch(void* const* d_in, const int* in_sizes, int n_in,
                              void* d_out, int out_size, void* d_ws, size_t ws_size,
                              hipStream_t stream) {
    const float* X = (const float*)d_in[0];
    const float* W = (const float*)d_in[1];
    float* out = (float*)d_out;
    float4* WT4 = (float4*)d_ws;   // 128 * 512 float4 = 1 MiB

    MinPlus_wt4_pack<<<dim3(OUT_DIM / 64, IN_DIM / 64), 256, 0, stream>>>(W, WT4);

    MinPlus_70832600646269_kernel<<<dim3(OUT_DIM / 256, B_DIM / 4), 1024, 0, stream>>>(X, WT4, out);
}

// Round 8
// 21.858 us; speedup vs baseline: 4.5961x; 1.1996x over previous
//
#include <hip/hip_runtime.h>
#include <math.h>

// Tropical (min-plus) matmul: out[b, j] = min_i (X[b, i] + W[j, i])
// X: [1024][512] fp32, W: [512][512] fp32, out: [1024][512] fp32.
//
// Round 8: fix the W-traffic + overlap problems found in round 7's accounting.
//  - W traffic = 1 GB / b_tile. b_tile 4->8 halves it (128 MB, all L2-resident)
//    and grid (2 x 128) = 256 blocks = exactly 1 block/CU, ONE invocation.
//  - W double-buffered in 8-k quarters (live 32 + prefetch 32 VGPR): the next
//    quarter's 8 float4 loads issue before the current quarter's 384-instr
//    b-loop -> VMEM hides under compute instead of serializing.
//  - TN=4 kept: per (b, quarter): 2 broadcast ds_read_b128 (24 LDS cyc/CU)
//    feeds 48 VALU instr (96 cyc across 4 SIMDs) -> pipes balanced.
//  - VGPR ~115 (acc 32 + w 64 + x/addr) under the 1024-thread 128 cap.
//  - LDS: Xs 8 KB + part[16][8][256] 128 KB = 136 KB, 1 block/CU.

#define B_DIM   1024
#define IN_DIM  512
#define OUT_DIM 512

// ---------------- prepass: WT4[k4][j] = { W[j][4k4..4k4+3] } ----------------
__global__ __launch_bounds__(256)
void MinPlus_wt4_pack(const float* __restrict__ W, float4* __restrict__ WT4) {
    __shared__ float Ls[64][68];
    const int tid = threadIdx.x;
    const int j0 = blockIdx.x * 64;
    const int k0 = blockIdx.y * 64;

#pragma unroll
    for (int r = 0; r < 4; ++r) {
        const int jj = (tid >> 4) + r * 16;
        const int kq = tid & 15;
        const float4 v = *reinterpret_cast<const float4*>(&W[(j0 + jj) * IN_DIM + k0 + 4 * kq]);
        *reinterpret_cast<float4*>(&Ls[jj][4 * kq]) = v;
    }
    __syncthreads();

    const int jj  = tid & 63;
    const int k4b = tid >> 6;
#pragma unroll
    for (int r = 0; r < 4; ++r) {
        const int k4l = r * 4 + k4b;
        const float4 v = *reinterpret_cast<const float4*>(&Ls[jj][4 * k4l]);
        WT4[(size_t)(blockIdx.y * 16 + k4l) * OUT_DIM + j0 + jj] = v;
    }
}

// ---------------- main ----------------
__global__ __launch_bounds__(1024)
void MinPlus_70832600646269_kernel(const float* __restrict__ X,
                                   const float4* __restrict__ WT4,
                                   float* __restrict__ out)
{
    __shared__ float Xs[8][IN_DIM];      // 16 KB? no: 8*512*4 = 16 KB... (8 KB per 4 rows) -> 16 KB total
    __shared__ float part[16][8][256];   // 128 KB: [k-chunk][b][j-local]

    const int tid  = threadIdx.x;
    const int lane = tid & 63;
    const int wid  = tid >> 6;           // 0..15: k-chunk [32wid, 32wid+32)
    const int j0   = blockIdx.x * 256;
    const int b0   = blockIdx.y * 8;

    // ---- stage X tile: 1024 float4 (16 KB), one per thread, fully coalesced ----
    reinterpret_cast<float4*>(&Xs[0][0])[tid] =
        reinterpret_cast<const float4*>(X + (size_t)b0 * IN_DIM)[tid];

    float acc[8][4];                     // [b][jq]
#pragma unroll
    for (int b = 0; b < 8; ++b)
#pragma unroll
        for (int jq = 0; jq < 4; ++jq) acc[b][jq] = INFINITY;

    // ---- W double-buffer: 8-k quarters (2 k4-groups x 4 jq = 8 float4) ----
    float4 w[2][2][4];
#pragma unroll
    for (int q2 = 0; q2 < 2; ++q2)
#pragma unroll
        for (int jq = 0; jq < 4; ++jq)
            w[0][q2][jq] = WT4[(size_t)(wid * 8 + q2) * OUT_DIM + j0 + jq * 64 + lane];

    __syncthreads();                     // Xs ready

#pragma unroll
    for (int qt = 0; qt < 4; ++qt) {     // four 8-k quarters of this wave's 32-k chunk
        const int cur = qt & 1, nxt = cur ^ 1;
        if (qt < 3) {                    // prefetch next quarter (overlaps b-loop)
#pragma unroll
            for (int q2 = 0; q2 < 2; ++q2)
#pragma unroll
                for (int jq = 0; jq < 4; ++jq)
                    w[nxt][q2][jq] =
                        WT4[(size_t)(wid * 8 + (qt + 1) * 2 + q2) * OUT_DIM + j0 + jq * 64 + lane];
        }
#pragma unroll
        for (int b = 0; b < 8; ++b) {
            const float4* __restrict__ xq =
                reinterpret_cast<const float4*>(&Xs[b][wid * 32 + qt * 8]);
#pragma unroll
            for (int q2 = 0; q2 < 2; ++q2) {
                const float4 x = xq[q2];          // uniform-address broadcast
#pragma unroll
                for (int jq = 0; jq < 4; ++jq) {
                    const float4 u = w[cur][q2][jq];
                    acc[b][jq] = fminf(fminf(acc[b][jq], u.x + x.x), u.y + x.y);  // v_min3
                    acc[b][jq] = fminf(fminf(acc[b][jq], u.z + x.z), u.w + x.w);  // v_min3
                }
            }
        }
    }

    // ---- per-wave partials (consecutive lanes -> consecutive addrs) ----
#pragma unroll
    for (int b = 0; b < 8; ++b)
#pragma unroll
        for (int jq = 0; jq < 4; ++jq)
            part[wid][b][jq * 64 + lane] = acc[b][jq];

    __syncthreads();

    // ---- combine 16 k-chunks: threads 0..511, one float4 of output each ----
    if (tid < 512) {
        const int b  = tid >> 6;          // 0..7
        const int j4 = (tid & 63) * 4;    // 0..252
        float4 m = *reinterpret_cast<const float4*>(&part[0][b][j4]);
#pragma unroll
        for (int p = 1; p < 16; ++p) {
            const float4 v = *reinterpret_cast<const float4*>(&part[p][b][j4]);
            m.x = fminf(m.x, v.x);
            m.y = fminf(m.y, v.y);
            m.z = fminf(m.z, v.z);
            m.w = fminf(m.w, v.w);
        }
        *reinterpret_cast<float4*>(&out[(size_t)(b0 + b) * OUT_DIM + j0 + j4]) = m;
    }
}

extern "C" void kernel_launch(void* const* d_in, const int* in_sizes, int n_in,
                              void* d_out, int out_size, void* d_ws, size_t ws_size,
                              hipStream_t stream) {
    const float* X = (const float*)d_in[0];
    const float* W = (const float*)d_in[1];
    float* out = (float*)d_out;
    float4* WT4 = (float4*)d_ws;   // 128 * 512 float4 = 1 MiB

    MinPlus_wt4_pack<<<dim3(OUT_DIM / 64, IN_DIM / 64), 256, 0, stream>>>(W, WT4);

    MinPlus_70832600646269_kernel<<<dim3(OUT_DIM / 256, B_DIM / 8), 1024, 0, stream>>>(X, WT4, out);
}